// Round 14
// baseline (1232.086 us; speedup 1.0000x reference)
//
#include <hip/hip_runtime.h>

#define NN 100000
#define NE 1600000
#define FF 128
#define KK 25000
#define NB ((NN + 255) / 256)    // 391 blocks of 256 over nodes
#define BM 64
#define BK 32
#define GEMM_GRID ((NN + BM - 1) / BM)

// radix CSR build params
#define BKT_SHIFT 11
#define NPBK (1 << BKT_SHIFT)                 // 2048 nodes per bucket
#define NBKT2 ((NN + NPBK - 1) >> BKT_SHIFT)  // 49 buckets
#define NBLKA 512
#define CHUNKA ((NE + NBLKA - 1) / NBLKA)     // 3125 edges per block

typedef __attribute__((ext_vector_type(8))) short short8v;   // 8 bf16 (4 VGPRs)
typedef __attribute__((ext_vector_type(4))) float float4v;   // MFMA C/D

// ---------- bf16 helpers ----------
__device__ __forceinline__ unsigned short f2b(float f) {
  unsigned u = __float_as_uint(f);
  u += 0x7FFFu + ((u >> 16) & 1u);  // round-to-nearest-even
  return (unsigned short)(u >> 16);
}
__device__ __forceinline__ unsigned pack2(float lo, float hi) {
  return (unsigned)f2b(lo) | ((unsigned)f2b(hi) << 16);
}

// ================= radix CSR build (atomic-free scatter, packed 4B pairs) ======
__global__ __launch_bounds__(256) void k_histA(const int* __restrict__ tgt,
                                               int* __restrict__ histg) {
  __shared__ int h[NBKT2];
  for (int i = threadIdx.x; i < NBKT2; i += 256) h[i] = 0;
  __syncthreads();
  int b = blockIdx.x;
  int e0 = b * CHUNKA, e1 = min(e0 + CHUNKA, NE);
  for (int e = e0 + threadIdx.x; e < e1; e += 256)
    atomicAdd(&h[tgt[e] >> BKT_SHIFT], 1);
  __syncthreads();
  for (int i = threadIdx.x; i < NBKT2; i += 256) histg[i * NBLKA + b] = h[i];
}

__global__ __launch_bounds__(1024) void k_scanA(int* __restrict__ histg,
                                                int* __restrict__ bbase) {
  const int M = NBKT2 * NBLKA;
  const int C = (M + 1023) / 1024;
  __shared__ int part[1024];
  __shared__ int tmp[1024];
  int t = threadIdx.x;
  int i0 = t * C;
  int iend = min(i0 + C, M);
  int s = 0;
  for (int i = i0; i < iend; ++i) s += histg[i];
  part[t] = s;
  __syncthreads();
  int* A = part;
  int* B = tmp;
  for (int off = 1; off < 1024; off <<= 1) {
    int v = A[t] + (t >= off ? A[t - off] : 0);
    B[t] = v;
    __syncthreads();
    int* sw = A; A = B; B = sw;
  }
  int run = (t > 0) ? A[t - 1] : 0;
  for (int i = i0; i < iend; ++i) {
    int v = histg[i];
    histg[i] = run;
    run += v;
  }
  __syncthreads();
  if (t < NBKT2) bbase[t] = histg[t * NBLKA];
  if (t == 0) bbase[NBKT2] = NE;
}

__global__ __launch_bounds__(256) void k_scatterA(const int* __restrict__ src,
                                                  const int* __restrict__ tgt,
                                                  const int* __restrict__ histg,
                                                  int* __restrict__ pairs) {
  __shared__ int cur[NBKT2];
  int b = blockIdx.x;
  for (int i = threadIdx.x; i < NBKT2; i += 256) cur[i] = histg[i * NBLKA + b];
  __syncthreads();
  int e0 = b * CHUNKA, e1 = min(e0 + CHUNKA, NE);
  for (int e = e0 + threadIdx.x; e < e1; e += 256) {
    int t = tgt[e];
    int p = atomicAdd(&cur[t >> BKT_SHIFT], 1);
    pairs[p] = (src[e] << BKT_SHIFT) | (t & (NPBK - 1));
  }
}

__global__ __launch_bounds__(1024) void k_bucketB(const int* __restrict__ pairs,
                                                  const int* __restrict__ bbase,
                                                  int* __restrict__ offsets,
                                                  int* __restrict__ csr) {
  __shared__ int cnt[NPBK];
  __shared__ int part[1024];
  __shared__ int tmp[1024];
  int b = blockIdx.x;
  int t = threadIdx.x;
  int lo = b << BKT_SHIFT;
  int nloc = min(NPBK, NN - lo);
  int base = bbase[b];
  int cntE = bbase[b + 1] - base;
  cnt[t] = 0;
  cnt[t + 1024] = 0;
  __syncthreads();
  for (int p = t; p < cntE; p += 1024)
    atomicAdd(&cnt[pairs[base + p] & (NPBK - 1)], 1);
  __syncthreads();
  int a0 = cnt[2 * t];
  int a1 = cnt[2 * t + 1];
  part[t] = a0 + a1;
  __syncthreads();
  int* A = part;
  int* B = tmp;
  for (int off = 1; off < 1024; off <<= 1) {
    int v = A[t] + (t >= off ? A[t - off] : 0);
    B[t] = v;
    __syncthreads();
    int* sw = A; A = B; B = sw;
  }
  int o0 = (t > 0) ? A[t - 1] : 0;
  int o1 = o0 + a0;
  if (2 * t < nloc) offsets[lo + 2 * t] = base + o0;
  if (2 * t + 1 < nloc) offsets[lo + 2 * t + 1] = base + o1;
  __syncthreads();
  cnt[2 * t] = o0;
  cnt[2 * t + 1] = o1;
  __syncthreads();
  for (int p = t; p < cntE; p += 1024) {
    int v = pairs[base + p];
    int l = v & (NPBK - 1);
    int pos = atomicAdd(&cnt[l], 1);
    csr[base + pos] = v >> BKT_SHIFT;
  }
  if (b == NBKT2 - 1 && t == 0) offsets[NN] = NE;
}

// ---------- f32 mean aggregation: 1 wave per node, 2 rows per VMEM instr ----------
__global__ __launch_bounds__(256) void k_agg(const float* __restrict__ vals,
                                             const int* __restrict__ csr,
                                             const int* __restrict__ offsets,
                                             float* __restrict__ outv) {
  int w = threadIdx.x >> 6;
  int lane = threadIdx.x & 63;
  int half = lane >> 5;
  int li = lane & 31;
  int node = blockIdx.x * 4 + w;
  if (node >= NN) return;
  int beg = offsets[node];
  int end = offsets[node + 1];
  int deg = end - beg;
  float a0 = 0.f, a1 = 0.f, a2 = 0.f, a3 = 0.f;
  int e = beg;
  int e8 = beg + (deg & ~7);
  for (; e < e8; e += 8) {
    float4 v[4];
#pragma unroll
    for (int q = 0; q < 4; ++q) {
      int j = csr[e + 2 * q + half];
      v[q] = *reinterpret_cast<const float4*>(&vals[(size_t)j * FF + li * 4]);
    }
#pragma unroll
    for (int q = 0; q < 4; ++q) {
      a0 += v[q].x; a1 += v[q].y; a2 += v[q].z; a3 += v[q].w;
    }
  }
  for (; e + 2 <= end; e += 2) {
    int j = csr[e + half];
    float4 v = *reinterpret_cast<const float4*>(&vals[(size_t)j * FF + li * 4]);
    a0 += v.x; a1 += v.y; a2 += v.z; a3 += v.w;
  }
  if (e < end && half == 0) {
    int j = csr[e];
    float4 v = *reinterpret_cast<const float4*>(&vals[(size_t)j * FF + li * 4]);
    a0 += v.x; a1 += v.y; a2 += v.z; a3 += v.w;
  }
  a0 += __shfl_xor(a0, 32, 64);
  a1 += __shfl_xor(a1, 32, 64);
  a2 += __shfl_xor(a2, 32, 64);
  a3 += __shfl_xor(a3, 32, 64);
  if (half == 0) {
    float inv = 1.0f / (float)(deg > 0 ? deg : 1);
    *reinterpret_cast<float4*>(&outv[(size_t)node * FF + li * 4]) =
        make_float4(a0 * inv, a1 * inv, a2 * inv, a3 * inv);
  }
}

// ---------- bf16 mean aggregation: 1 wave per node, 4 rows per VMEM instr ----------
template <bool GATED>
__global__ __launch_bounds__(256) void k_agg_bf(const unsigned* __restrict__ vals,
                                                const int* __restrict__ csr,
                                                const int* __restrict__ offsets,
                                                const float* __restrict__ sel,
                                                unsigned* __restrict__ outv) {
  int w = threadIdx.x >> 6;
  int lane = threadIdx.x & 63;
  int qt = lane >> 4;
  int li = lane & 15;
  int node = blockIdx.x * 4 + w;
  if (node >= NN) return;
  int beg = offsets[node];
  int end = offsets[node + 1];
  int deg = end - beg;
  float a0 = 0.f, a1 = 0.f, a2 = 0.f, a3 = 0.f;
  float a4 = 0.f, a5 = 0.f, a6 = 0.f, a7 = 0.f;
  int e = beg;
  int e8 = beg + (deg & ~7);
  for (; e < e8; e += 8) {
    uint4 u[2];
#pragma unroll
    for (int q = 0; q < 2; ++q) {
      int j = csr[e + 4 * q + qt];
      u[q] = (!GATED || sel[j] != 0.f)
                 ? *reinterpret_cast<const uint4*>(&vals[(size_t)j * (FF / 2) + li * 4])
                 : make_uint4(0u, 0u, 0u, 0u);
    }
#pragma unroll
    for (int q = 0; q < 2; ++q) {
      a0 += __uint_as_float(u[q].x << 16);
      a1 += __uint_as_float(u[q].x & 0xFFFF0000u);
      a2 += __uint_as_float(u[q].y << 16);
      a3 += __uint_as_float(u[q].y & 0xFFFF0000u);
      a4 += __uint_as_float(u[q].z << 16);
      a5 += __uint_as_float(u[q].z & 0xFFFF0000u);
      a6 += __uint_as_float(u[q].w << 16);
      a7 += __uint_as_float(u[q].w & 0xFFFF0000u);
    }
  }
  for (; e + 4 <= end; e += 4) {
    int j = csr[e + qt];
    uint4 u = (!GATED || sel[j] != 0.f)
                  ? *reinterpret_cast<const uint4*>(&vals[(size_t)j * (FF / 2) + li * 4])
                  : make_uint4(0u, 0u, 0u, 0u);
    a0 += __uint_as_float(u.x << 16);
    a1 += __uint_as_float(u.x & 0xFFFF0000u);
    a2 += __uint_as_float(u.y << 16);
    a3 += __uint_as_float(u.y & 0xFFFF0000u);
    a4 += __uint_as_float(u.z << 16);
    a5 += __uint_as_float(u.z & 0xFFFF0000u);
    a6 += __uint_as_float(u.w << 16);
    a7 += __uint_as_float(u.w & 0xFFFF0000u);
  }
  int r = end - e;  // 0..3
  if (qt < r) {
    int j = csr[e + qt];
    uint4 u = (!GATED || sel[j] != 0.f)
                  ? *reinterpret_cast<const uint4*>(&vals[(size_t)j * (FF / 2) + li * 4])
                  : make_uint4(0u, 0u, 0u, 0u);
    a0 += __uint_as_float(u.x << 16);
    a1 += __uint_as_float(u.x & 0xFFFF0000u);
    a2 += __uint_as_float(u.y << 16);
    a3 += __uint_as_float(u.y & 0xFFFF0000u);
    a4 += __uint_as_float(u.z << 16);
    a5 += __uint_as_float(u.z & 0xFFFF0000u);
    a6 += __uint_as_float(u.w << 16);
    a7 += __uint_as_float(u.w & 0xFFFF0000u);
  }
  a0 += __shfl_xor(a0, 16, 64); a0 += __shfl_xor(a0, 32, 64);
  a1 += __shfl_xor(a1, 16, 64); a1 += __shfl_xor(a1, 32, 64);
  a2 += __shfl_xor(a2, 16, 64); a2 += __shfl_xor(a2, 32, 64);
  a3 += __shfl_xor(a3, 16, 64); a3 += __shfl_xor(a3, 32, 64);
  a4 += __shfl_xor(a4, 16, 64); a4 += __shfl_xor(a4, 32, 64);
  a5 += __shfl_xor(a5, 16, 64); a5 += __shfl_xor(a5, 32, 64);
  a6 += __shfl_xor(a6, 16, 64); a6 += __shfl_xor(a6, 32, 64);
  a7 += __shfl_xor(a7, 16, 64); a7 += __shfl_xor(a7, 32, 64);
  if (qt == 0) {
    float inv = 1.0f / (float)(deg > 0 ? deg : 1);
    uint4 o;
    o.x = pack2(a0 * inv, a1 * inv);
    o.y = pack2(a2 * inv, a3 * inv);
    o.z = pack2(a4 * inv, a5 * inv);
    o.w = pack2(a6 * inv, a7 * inv);
    *reinterpret_cast<uint4*>(&outv[(size_t)node * (FF / 2) + li * 4]) = o;
  }
}

// ---------- tiled SGEMM (f32) — compress (EPI 0, DUAL, fused score + hist rd 1) ----
template <int EPI, bool DUAL, bool ABF16>
__global__ __launch_bounds__(256) void k_gemm4(const void* __restrict__ Araw,
                                               const float* __restrict__ W,
                                               const float* __restrict__ A2,
                                               const float* __restrict__ W2,
                                               const float* __restrict__ bias,
                                               float* __restrict__ outv,
                                               const float* __restrict__ wsc,
                                               const float* __restrict__ bsc,
                                               float* __restrict__ score_out,
                                               unsigned* __restrict__ hist) {
  __shared__ float As[BK][BM + 4];
  __shared__ float Ws[BK][FF];
  const int tid = threadIdx.x;
  const int tx = tid & 15;
  const int ty = tid >> 4;
  const int m0 = blockIdx.x * BM;

  float acc[4][8];
#pragma unroll
  for (int r = 0; r < 4; ++r)
#pragma unroll
    for (int j = 0; j < 8; ++j) acc[r][j] = 0.f;

  const int NPASS = DUAL ? 2 : 1;
  for (int pass = 0; pass < NPASS; ++pass) {
    const float* Wp = (pass == 0) ? W : W2;
    for (int kt = 0; kt < FF; kt += BK) {
      __syncthreads();
      if (pass == 0 && ABF16) {
        const unsigned* Ab = (const unsigned*)Araw;
#pragma unroll
        for (int t = 0; t < 4; ++t) {
          int i = tid + t * 256;
          int row = i >> 4;
          int cu = i & 15;
          int gr = m0 + row;
          unsigned u = (gr < NN) ? Ab[(size_t)gr * (FF / 2) + (kt >> 1) + cu] : 0u;
          As[cu * 2 + 0][row] = __uint_as_float(u << 16);
          As[cu * 2 + 1][row] = __uint_as_float(u & 0xFFFF0000u);
        }
      } else {
        const float* Ag = (pass == 0) ? (const float*)Araw : A2;
#pragma unroll
        for (int t = 0; t < 2; ++t) {
          int i = tid + t * 256;
          int row = i >> 3;
          int c8 = i & 7;
          int gr = m0 + row;
          float4 v = make_float4(0.f, 0.f, 0.f, 0.f);
          if (gr < NN) v = *(const float4*)&Ag[(size_t)gr * FF + kt + c8 * 4];
          As[c8 * 4 + 0][row] = v.x;
          As[c8 * 4 + 1][row] = v.y;
          As[c8 * 4 + 2][row] = v.z;
          As[c8 * 4 + 3][row] = v.w;
        }
      }
#pragma unroll
      for (int t = 0; t < 4; ++t) {
        int i = tid + t * 256;
        int kr = i >> 5;
        int c4 = i & 31;
        *(float4*)&Ws[kr][c4 * 4] =
            *(const float4*)&Wp[(size_t)(kt + kr) * FF + c4 * 4];
      }
      __syncthreads();
#pragma unroll
      for (int k = 0; k < BK; ++k) {
        float4 a = *(const float4*)&As[k][ty * 4];
        float4 w0 = *(const float4*)&Ws[k][tx * 4];
        float4 w1 = *(const float4*)&Ws[k][tx * 4 + 64];
        float av[4] = {a.x, a.y, a.z, a.w};
        float wv[8] = {w0.x, w0.y, w0.z, w0.w, w1.x, w1.y, w1.z, w1.w};
#pragma unroll
        for (int r = 0; r < 4; ++r)
#pragma unroll
          for (int j = 0; j < 8; ++j) acc[r][j] = fmaf(av[r], wv[j], acc[r][j]);
      }
    }
  }

  float4 b0 = *(const float4*)&bias[tx * 4];
  float4 b1 = *(const float4*)&bias[tx * 4 + 64];
  float bs[8] = {b0.x, b0.y, b0.z, b0.w, b1.x, b1.y, b1.z, b1.w};

  if constexpr (EPI == 0) {
    __shared__ float sp[BM][17];
    float4 s0 = *(const float4*)&wsc[tx * 4];
    float4 s1 = *(const float4*)&wsc[tx * 4 + 64];
    float sv[8] = {s0.x, s0.y, s0.z, s0.w, s1.x, s1.y, s1.z, s1.w};
#pragma unroll
    for (int r = 0; r < 4; ++r) {
      int gi = m0 + ty * 4 + r;
      if (gi >= NN) continue;
      size_t base = (size_t)gi * FF;
      float v[8];
      float p = 0.f;
#pragma unroll
      for (int j = 0; j < 8; ++j) {
        v[j] = acc[r][j] + bs[j];
        p = fmaf(v[j], sv[j], p);
      }
      sp[ty * 4 + r][tx] = p;
      *(float4*)&outv[base + tx * 4] = make_float4(v[0], v[1], v[2], v[3]);
      *(float4*)&outv[base + tx * 4 + 64] = make_float4(v[4], v[5], v[6], v[7]);
    }
    __syncthreads();
    if (tid < BM) {
      int gi = m0 + tid;
      if (gi < NN) {
        float s = 0.f;
#pragma unroll
        for (int t = 0; t < 16; ++t) s += sp[tid][t];  // fixed order
        float z = s + bsc[0];
        float sc = 1.0f / (1.0f + expf(-z));
        score_out[gi] = sc;
        // fused top-K round-1 histogram (top 8 bits of score)
        atomicAdd(&hist[__float_as_uint(sc) >> 24], 1u);
      }
    }
  }
}

// ---------- pack W (f32 [128][128]) into MFMA B-fragment bf16 layout ----------
__global__ __launch_bounds__(256) void k_packW(const float* __restrict__ W,
                                               unsigned* __restrict__ Wpk) {
  int i = blockIdx.x * 256 + threadIdx.x;  // 0..2047
  int kt = i >> 9;
  int rem = i & 511;
  int c = rem >> 2;
  int h = rem & 3;
  int kb = kt * 32 + h * 8;
  uint4 o;
  o.x = pack2(W[(kb + 0) * FF + c], W[(kb + 1) * FF + c]);
  o.y = pack2(W[(kb + 2) * FF + c], W[(kb + 3) * FF + c]);
  o.z = pack2(W[(kb + 4) * FF + c], W[(kb + 5) * FF + c]);
  o.w = pack2(W[(kb + 6) * FF + c], W[(kb + 7) * FF + c]);
  *reinterpret_cast<uint4*>(&Wpk[(size_t)i * 4]) = o;
}

// ---------- MFMA bf16 GEMM for decompress (round-13 verified) ----------
template <int EPI>
__global__ __launch_bounds__(256) void k_gemm_mfma(const unsigned* __restrict__ A,
                                                   const unsigned* __restrict__ Wpk,
                                                   const float* __restrict__ bias,
                                                   const float* __restrict__ aux,
                                                   const float* __restrict__ score,
                                                   const float* __restrict__ sel,
                                                   float* __restrict__ outv,
                                                   unsigned short* __restrict__ obf) {
  __shared__ unsigned As[64][68];
  const int tid = threadIdx.x;
  const int wv = tid >> 6;
  const int l = tid & 63;
  const int lg = l >> 4;
  const int lr = l & 15;
  const int m0 = blockIdx.x * 64;

#pragma unroll
  for (int p = 0; p < 4; ++p) {
    int i = tid + p * 256;
    int row = i >> 4, c4 = (i & 15) * 4;
    int gr = m0 + row;
    uint4 v = make_uint4(0u, 0u, 0u, 0u);
    if (gr < NN) v = *reinterpret_cast<const uint4*>(&A[(size_t)gr * 64 + c4]);
    *reinterpret_cast<uint4*>(&As[row][c4]) = v;
  }
  __syncthreads();

  int arow = wv * 16 + lr;
  short8v a[4];
#pragma unroll
  for (int kt = 0; kt < 4; ++kt)
    a[kt] = *reinterpret_cast<const short8v*>(&As[arow][kt * 16 + lg * 4]);

#pragma unroll
  for (int ct = 0; ct < 8; ++ct) {
    float4v acc = {0.f, 0.f, 0.f, 0.f};
    int col = ct * 16 + lr;
#pragma unroll
    for (int kt = 0; kt < 4; ++kt) {
      short8v b = *reinterpret_cast<const short8v*>(
          &Wpk[(size_t)((kt * 128 + col) * 4 + lg) * 4]);
      acc = __builtin_amdgcn_mfma_f32_16x16x32_bf16(a[kt], b, acc, 0, 0, 0);
    }
    float bcol = bias[col];
#pragma unroll
    for (int i = 0; i < 4; ++i) {
      int gi = m0 + wv * 16 + lg * 4 + i;
      if (gi >= NN) continue;
      float g = acc[i] + bcol;
      size_t oi = (size_t)gi * FF + col;
      if (EPI == 1) {
        float se = sel[gi];
        float v;
        if (se != 0.f) {
          v = fmaxf(aux[oi] * score[gi], 0.f);
          outv[oi] = v;
        } else {
          v = fmaxf(g, 0.f);
        }
        obf[(size_t)gi * FF + col] = f2b(v);
      } else {
        float se = sel[gi];
        outv[oi] = (se != 0.f) ? aux[oi] : g;
      }
    }
  }
}

// ===== top-K: 4x8-bit radix on score bits + analytic lowest-index tie-break =====
__global__ void k_init_state(unsigned* state) {
  state[0] = 0u;   // 32-bit score-bit prefix
  state[1] = KK;   // remaining rank
}

// standalone hist rounds (bits_fixed = 8,16,24); round 1 fused into gemm0
__global__ __launch_bounds__(256) void k_hist(const float* __restrict__ score,
                                              const unsigned* __restrict__ state,
                                              unsigned* __restrict__ hist,
                                              int bits_fixed) {
  __shared__ unsigned lh[256];
  lh[threadIdx.x] = 0;
  __syncthreads();
  unsigned prefix = state[0];
  int i = blockIdx.x * 256 + threadIdx.x;
  if (i < NN) {
    unsigned bits = __float_as_uint(score[i]);
    if (((bits ^ prefix) >> (32 - bits_fixed)) == 0u) {
      unsigned b = (bits >> (24 - bits_fixed)) & 0xFFu;
      atomicAdd(&lh[b], 1u);
    }
  }
  __syncthreads();
  if (lh[threadIdx.x]) atomicAdd(&hist[threadIdx.x], lh[threadIdx.x]);
}

__global__ __launch_bounds__(256) void k_select_round(unsigned* __restrict__ state,
                                                      unsigned* __restrict__ hist,
                                                      int bits_fixed) {
  __shared__ unsigned h[256];
  int t = threadIdx.x;
  h[t] = hist[t];
  hist[t] = 0;  // ready for next round
  __syncthreads();
  if (t == 0) {
    unsigned rem = state[1];
    unsigned prefix = state[0];
    unsigned cum = 0;
    int bstar = 0;
    for (int b = 255; b >= 0; --b) {
      unsigned c = h[b];
      if (cum + c >= rem) { bstar = b; break; }
      cum += c;
    }
    rem -= cum;
    prefix |= ((unsigned)bstar) << (24 - bits_fixed);
    state[0] = prefix;
    state[1] = rem;
  }
}

__global__ __launch_bounds__(256) void k_eqcount(const float* __restrict__ score,
                                                 const unsigned* __restrict__ state,
                                                 int* __restrict__ eqc) {
  __shared__ int s[256];
  int i = blockIdx.x * 256 + threadIdx.x;
  unsigned T = state[0];
  int eq = (i < NN && __float_as_uint(score[i]) == T) ? 1 : 0;
  s[threadIdx.x] = eq;
  __syncthreads();
  for (int off = 128; off > 0; off >>= 1) {
    if (threadIdx.x < off) s[threadIdx.x] += s[threadIdx.x + off];
    __syncthreads();
  }
  if (threadIdx.x == 0) eqc[blockIdx.x] = s[0];
}

__global__ __launch_bounds__(512) void k_eqscan(const int* __restrict__ eqc,
                                                int* __restrict__ eqoff) {
  __shared__ int s[512];
  __shared__ int tmp[512];
  int t = threadIdx.x;
  int own = (t < NB) ? eqc[t] : 0;
  s[t] = own;
  __syncthreads();
  int* A = s;
  int* B = tmp;
  for (int off = 1; off < 512; off <<= 1) {
    int v = A[t] + (t >= off ? A[t - off] : 0);
    B[t] = v;
    __syncthreads();
    int* sw = A; A = B; B = sw;
  }
  if (t < NB) eqoff[t] = A[t] - own;  // exclusive
}

__global__ __launch_bounds__(256) void k_tb(const float* __restrict__ score,
                                            const unsigned* __restrict__ state,
                                            const int* __restrict__ eqoff,
                                            float* __restrict__ sel) {
  __shared__ int s[256];
  __shared__ int tmp[256];
  int blk = blockIdx.x;
  int i = blk * 256 + threadIdx.x;
  unsigned T = state[0];
  unsigned rem = state[1];
  unsigned bits = (i < NN) ? __float_as_uint(score[i]) : 0u;
  int eq = (i < NN && bits == T) ? 1 : 0;
  s[threadIdx.x] = eq;
  __syncthreads();
  int* A = s;
  int* B = tmp;
  for (int off = 1; off < 256; off <<= 1) {
    int v = A[threadIdx.x] + (threadIdx.x >= off ? A[threadIdx.x - off] : 0);
    B[threadIdx.x] = v;
    __syncthreads();
    int* sw = A; A = B; B = sw;
  }
  int excl = A[threadIdx.x] - eq;
  if (i < NN) {
    float sv = 0.f;
    if (bits > T) sv = 1.f;
    else if (eq && (unsigned)(eqoff[blk] + excl) < rem) sv = 1.f;
    sel[i] = sv;
  }
}

// ---------- gated z pack (reads sel; selected rows only) ----------
__global__ __launch_bounds__(256) void k_gate_zg(const float* __restrict__ h,
                                                 const float* __restrict__ score,
                                                 const float* __restrict__ sel,
                                                 unsigned* __restrict__ zg) {
  int w = threadIdx.x >> 6;
  int lane = threadIdx.x & 63;
  int node = blockIdx.x * 4 + w;
  if (node >= NN) return;
  if (sel[node] == 0.f) return;
  float s = score[node];
  float2 v = *reinterpret_cast<const float2*>(&h[(size_t)node * FF + lane * 2]);
  zg[(size_t)node * (FF / 2) + lane] = pack2(v.x * s, v.y * s);
}

// ---------- launch ----------
extern "C" void kernel_launch(void* const* d_in, const int* in_sizes, int n_in,
                              void* d_out, int out_size, void* d_ws, size_t ws_size,
                              hipStream_t stream) {
  const float* x = (const float*)d_in[0];
  const int* src = (const int*)d_in[1];
  const int* tgt = (const int*)d_in[2];
  const float* W_self = (const float*)d_in[3];
  const float* W_neigh = (const float*)d_in[4];
  const float* b_pack = (const float*)d_in[5];
  const float* w_score = (const float*)d_in[6];
  const float* b_score = (const float*)d_in[7];
  const float* W_u1 = (const float*)d_in[8];
  const float* b_u1 = (const float*)d_in[9];
  const float* W_u2 = (const float*)d_in[10];
  const float* b_u2 = (const float*)d_in[11];
  float* out = (float*)d_out;

  char* ws = (char*)d_ws;
  size_t off = 0;
  auto alloc = [&](size_t bytes) -> char* {
    char* p = ws + off;
    off += (bytes + 255) & ~(size_t)255;
    return p;
  };
  int* offsets = (int*)alloc((size_t)(NN + 1) * 4);
  int* csr = (int*)alloc((size_t)NE * 4);
  int* histg = (int*)alloc((size_t)NBKT2 * NBLKA * 4);
  int* bbase = (int*)alloc((size_t)(NBKT2 + 1) * 4);
  float* score = (float*)alloc((size_t)NN * 4);
  float* sel = (float*)alloc((size_t)NN * 4);
  unsigned* hist = (unsigned*)alloc(256 * 4);
  unsigned* state = (unsigned*)alloc(64);
  int* eqc = (int*)alloc((size_t)NB * 4);
  int* eqoff = (int*)alloc((size_t)NB * 4);
  unsigned* pkW1 = (unsigned*)alloc(2048 * 16);
  unsigned* pkW2 = (unsigned*)alloc(2048 * 16);
  float* aggF = (float*)alloc((size_t)NN * FF * 4);  // 51.2 MB, multi-use:
  int* pairs = (int*)aggF;                            //   CSR build scratch (6.4 MB)
  unsigned* zdbf = (unsigned*)aggF;                   //   then z-bf16 / d-bf16
  unsigned* aggBF = (unsigned*)(aggF + (size_t)NN * (FF / 2));  // bf16 agg out
  float* bufB = out;  // h, then d, live in d_out

  hipMemsetAsync(hist, 0, 256 * 4, stream);
  k_init_state<<<1, 1, 0, stream>>>(state);
  k_packW<<<8, 256, 0, stream>>>(W_u1, pkW1);
  k_packW<<<8, 256, 0, stream>>>(W_u2, pkW2);

  // radix CSR build: histogram -> scan -> scatter packed pairs -> per-bucket fill
  k_histA<<<NBLKA, 256, 0, stream>>>(tgt, histg);
  k_scanA<<<1, 1024, 0, stream>>>(histg, bbase);
  k_scatterA<<<NBLKA, 256, 0, stream>>>(src, tgt, histg, pairs);
  k_bucketB<<<NBKT2, 1024, 0, stream>>>(pairs, bbase, offsets, csr);

  // ---- compress (f32; score + top-K round-1 histogram fused into gemm0) ----
  k_agg<<<NN / 4, 256, 0, stream>>>(x, csr, offsets, aggF);
  k_gemm4<0, true, false><<<GEMM_GRID, 256, 0, stream>>>(
      aggF, W_neigh, x, W_self, b_pack, bufB, w_score, b_score, score, hist);

  // ---- exact top-K: 4x8-bit radix on score bits + lowest-index tie-break ----
  k_select_round<<<1, 256, 0, stream>>>(state, hist, 0);
  for (int r = 1; r < 4; ++r) {
    k_hist<<<NB, 256, 0, stream>>>(score, state, hist, 8 * r);
    k_select_round<<<1, 256, 0, stream>>>(state, hist, 8 * r);
  }
  k_eqcount<<<NB, 256, 0, stream>>>(score, state, eqc);
  k_eqscan<<<1, 512, 0, stream>>>(eqc, eqoff);
  k_tb<<<NB, 256, 0, stream>>>(score, state, eqoff, sel);

  // ---- decompress (bf16 gathers + MFMA bf16 GEMMs; selected rows stay f32) ----
  k_gate_zg<<<NN / 4, 256, 0, stream>>>(bufB, score, sel, zdbf);
  k_agg_bf<true><<<NN / 4, 256, 0, stream>>>(zdbf, csr, offsets, sel, aggBF);
  k_gemm_mfma<1><<<GEMM_GRID, 256, 0, stream>>>(aggBF, pkW1, b_u1, bufB, score,
                                                sel, bufB,
                                                (unsigned short*)zdbf);
  k_agg_bf<false><<<NN / 4, 256, 0, stream>>>(zdbf, csr, offsets, nullptr, aggBF);
  k_gemm_mfma<2><<<GEMM_GRID, 256, 0, stream>>>(aggBF, pkW2, b_u2, bufB, nullptr,
                                                sel, out, nullptr);
}

// Round 15
// 549.365 us; speedup vs baseline: 2.2427x; 2.2427x over previous
//
#include <hip/hip_runtime.h>

#define NN 100000
#define NE 1600000
#define FF 128
#define KK 25000
#define NB ((NN + 255) / 256)    // 391 blocks of 256 over nodes
#define BM 64
#define BK 32
#define GEMM_GRID ((NN + BM - 1) / BM)

// radix CSR build params
#define BKT_SHIFT 11
#define NPBK (1 << BKT_SHIFT)                 // 2048 nodes per bucket
#define NBKT2 ((NN + NPBK - 1) >> BKT_SHIFT)  // 49 buckets
#define NBLKA 512
#define CHUNKA ((NE + NBLKA - 1) / NBLKA)     // 3125 edges per block

typedef __attribute__((ext_vector_type(8))) short short8v;   // 8 bf16 (4 VGPRs)
typedef __attribute__((ext_vector_type(4))) float float4v;   // MFMA C/D

// ---------- bf16 helpers ----------
__device__ __forceinline__ unsigned short f2b(float f) {
  unsigned u = __float_as_uint(f);
  u += 0x7FFFu + ((u >> 16) & 1u);  // round-to-nearest-even
  return (unsigned short)(u >> 16);
}
__device__ __forceinline__ unsigned pack2(float lo, float hi) {
  return (unsigned)f2b(lo) | ((unsigned)f2b(hi) << 16);
}

// ================= radix CSR build (atomic-free scatter, packed 4B pairs) ======
__global__ __launch_bounds__(256) void k_histA(const int* __restrict__ tgt,
                                               int* __restrict__ histg) {
  __shared__ int h[NBKT2];
  for (int i = threadIdx.x; i < NBKT2; i += 256) h[i] = 0;
  __syncthreads();
  int b = blockIdx.x;
  int e0 = b * CHUNKA, e1 = min(e0 + CHUNKA, NE);
  for (int e = e0 + threadIdx.x; e < e1; e += 256)
    atomicAdd(&h[tgt[e] >> BKT_SHIFT], 1);
  __syncthreads();
  for (int i = threadIdx.x; i < NBKT2; i += 256) histg[i * NBLKA + b] = h[i];
}

__global__ __launch_bounds__(1024) void k_scanA(int* __restrict__ histg,
                                                int* __restrict__ bbase) {
  const int M = NBKT2 * NBLKA;
  const int C = (M + 1023) / 1024;
  __shared__ int part[1024];
  __shared__ int tmp[1024];
  int t = threadIdx.x;
  int i0 = t * C;
  int iend = min(i0 + C, M);
  int s = 0;
  for (int i = i0; i < iend; ++i) s += histg[i];
  part[t] = s;
  __syncthreads();
  int* A = part;
  int* B = tmp;
  for (int off = 1; off < 1024; off <<= 1) {
    int v = A[t] + (t >= off ? A[t - off] : 0);
    B[t] = v;
    __syncthreads();
    int* sw = A; A = B; B = sw;
  }
  int run = (t > 0) ? A[t - 1] : 0;
  for (int i = i0; i < iend; ++i) {
    int v = histg[i];
    histg[i] = run;
    run += v;
  }
  __syncthreads();
  if (t < NBKT2) bbase[t] = histg[t * NBLKA];
  if (t == 0) bbase[NBKT2] = NE;
}

__global__ __launch_bounds__(256) void k_scatterA(const int* __restrict__ src,
                                                  const int* __restrict__ tgt,
                                                  const int* __restrict__ histg,
                                                  int* __restrict__ pairs) {
  __shared__ int cur[NBKT2];
  int b = blockIdx.x;
  for (int i = threadIdx.x; i < NBKT2; i += 256) cur[i] = histg[i * NBLKA + b];
  __syncthreads();
  int e0 = b * CHUNKA, e1 = min(e0 + CHUNKA, NE);
  for (int e = e0 + threadIdx.x; e < e1; e += 256) {
    int t = tgt[e];
    int p = atomicAdd(&cur[t >> BKT_SHIFT], 1);
    pairs[p] = (src[e] << BKT_SHIFT) | (t & (NPBK - 1));
  }
}

__global__ __launch_bounds__(1024) void k_bucketB(const int* __restrict__ pairs,
                                                  const int* __restrict__ bbase,
                                                  int* __restrict__ offsets,
                                                  int* __restrict__ csr) {
  __shared__ int cnt[NPBK];
  __shared__ int part[1024];
  __shared__ int tmp[1024];
  int b = blockIdx.x;
  int t = threadIdx.x;
  int lo = b << BKT_SHIFT;
  int nloc = min(NPBK, NN - lo);
  int base = bbase[b];
  int cntE = bbase[b + 1] - base;
  cnt[t] = 0;
  cnt[t + 1024] = 0;
  __syncthreads();
  for (int p = t; p < cntE; p += 1024)
    atomicAdd(&cnt[pairs[base + p] & (NPBK - 1)], 1);
  __syncthreads();
  int a0 = cnt[2 * t];
  int a1 = cnt[2 * t + 1];
  part[t] = a0 + a1;
  __syncthreads();
  int* A = part;
  int* B = tmp;
  for (int off = 1; off < 1024; off <<= 1) {
    int v = A[t] + (t >= off ? A[t - off] : 0);
    B[t] = v;
    __syncthreads();
    int* sw = A; A = B; B = sw;
  }
  int o0 = (t > 0) ? A[t - 1] : 0;
  int o1 = o0 + a0;
  if (2 * t < nloc) offsets[lo + 2 * t] = base + o0;
  if (2 * t + 1 < nloc) offsets[lo + 2 * t + 1] = base + o1;
  __syncthreads();
  cnt[2 * t] = o0;
  cnt[2 * t + 1] = o1;
  __syncthreads();
  for (int p = t; p < cntE; p += 1024) {
    int v = pairs[base + p];
    int l = v & (NPBK - 1);
    int pos = atomicAdd(&cnt[l], 1);
    csr[base + pos] = v >> BKT_SHIFT;
  }
  if (b == NBKT2 - 1 && t == 0) offsets[NN] = NE;
}

// ---------- f32 mean aggregation: 1 wave per node, 2 rows per VMEM instr ----------
__global__ __launch_bounds__(256) void k_agg(const float* __restrict__ vals,
                                             const int* __restrict__ csr,
                                             const int* __restrict__ offsets,
                                             float* __restrict__ outv) {
  int w = threadIdx.x >> 6;
  int lane = threadIdx.x & 63;
  int half = lane >> 5;
  int li = lane & 31;
  int node = blockIdx.x * 4 + w;
  if (node >= NN) return;
  int beg = offsets[node];
  int end = offsets[node + 1];
  int deg = end - beg;
  float a0 = 0.f, a1 = 0.f, a2 = 0.f, a3 = 0.f;
  int e = beg;
  int e8 = beg + (deg & ~7);
  for (; e < e8; e += 8) {
    float4 v[4];
#pragma unroll
    for (int q = 0; q < 4; ++q) {
      int j = csr[e + 2 * q + half];
      v[q] = *reinterpret_cast<const float4*>(&vals[(size_t)j * FF + li * 4]);
    }
#pragma unroll
    for (int q = 0; q < 4; ++q) {
      a0 += v[q].x; a1 += v[q].y; a2 += v[q].z; a3 += v[q].w;
    }
  }
  for (; e + 2 <= end; e += 2) {
    int j = csr[e + half];
    float4 v = *reinterpret_cast<const float4*>(&vals[(size_t)j * FF + li * 4]);
    a0 += v.x; a1 += v.y; a2 += v.z; a3 += v.w;
  }
  if (e < end && half == 0) {
    int j = csr[e];
    float4 v = *reinterpret_cast<const float4*>(&vals[(size_t)j * FF + li * 4]);
    a0 += v.x; a1 += v.y; a2 += v.z; a3 += v.w;
  }
  a0 += __shfl_xor(a0, 32, 64);
  a1 += __shfl_xor(a1, 32, 64);
  a2 += __shfl_xor(a2, 32, 64);
  a3 += __shfl_xor(a3, 32, 64);
  if (half == 0) {
    float inv = 1.0f / (float)(deg > 0 ? deg : 1);
    *reinterpret_cast<float4*>(&outv[(size_t)node * FF + li * 4]) =
        make_float4(a0 * inv, a1 * inv, a2 * inv, a3 * inv);
  }
}

// ---------- bf16 mean aggregation: 1 wave per node, 4 rows per VMEM instr ----------
template <bool GATED>
__global__ __launch_bounds__(256) void k_agg_bf(const unsigned* __restrict__ vals,
                                                const int* __restrict__ csr,
                                                const int* __restrict__ offsets,
                                                const float* __restrict__ sel,
                                                unsigned* __restrict__ outv) {
  int w = threadIdx.x >> 6;
  int lane = threadIdx.x & 63;
  int qt = lane >> 4;
  int li = lane & 15;
  int node = blockIdx.x * 4 + w;
  if (node >= NN) return;
  int beg = offsets[node];
  int end = offsets[node + 1];
  int deg = end - beg;
  float a0 = 0.f, a1 = 0.f, a2 = 0.f, a3 = 0.f;
  float a4 = 0.f, a5 = 0.f, a6 = 0.f, a7 = 0.f;
  int e = beg;
  int e8 = beg + (deg & ~7);
  for (; e < e8; e += 8) {
    uint4 u[2];
#pragma unroll
    for (int q = 0; q < 2; ++q) {
      int j = csr[e + 4 * q + qt];
      u[q] = (!GATED || sel[j] != 0.f)
                 ? *reinterpret_cast<const uint4*>(&vals[(size_t)j * (FF / 2) + li * 4])
                 : make_uint4(0u, 0u, 0u, 0u);
    }
#pragma unroll
    for (int q = 0; q < 2; ++q) {
      a0 += __uint_as_float(u[q].x << 16);
      a1 += __uint_as_float(u[q].x & 0xFFFF0000u);
      a2 += __uint_as_float(u[q].y << 16);
      a3 += __uint_as_float(u[q].y & 0xFFFF0000u);
      a4 += __uint_as_float(u[q].z << 16);
      a5 += __uint_as_float(u[q].z & 0xFFFF0000u);
      a6 += __uint_as_float(u[q].w << 16);
      a7 += __uint_as_float(u[q].w & 0xFFFF0000u);
    }
  }
  for (; e + 4 <= end; e += 4) {
    int j = csr[e + qt];
    uint4 u = (!GATED || sel[j] != 0.f)
                  ? *reinterpret_cast<const uint4*>(&vals[(size_t)j * (FF / 2) + li * 4])
                  : make_uint4(0u, 0u, 0u, 0u);
    a0 += __uint_as_float(u.x << 16);
    a1 += __uint_as_float(u.x & 0xFFFF0000u);
    a2 += __uint_as_float(u.y << 16);
    a3 += __uint_as_float(u.y & 0xFFFF0000u);
    a4 += __uint_as_float(u.z << 16);
    a5 += __uint_as_float(u.z & 0xFFFF0000u);
    a6 += __uint_as_float(u.w << 16);
    a7 += __uint_as_float(u.w & 0xFFFF0000u);
  }
  int r = end - e;  // 0..3
  if (qt < r) {
    int j = csr[e + qt];
    uint4 u = (!GATED || sel[j] != 0.f)
                  ? *reinterpret_cast<const uint4*>(&vals[(size_t)j * (FF / 2) + li * 4])
                  : make_uint4(0u, 0u, 0u, 0u);
    a0 += __uint_as_float(u.x << 16);
    a1 += __uint_as_float(u.x & 0xFFFF0000u);
    a2 += __uint_as_float(u.y << 16);
    a3 += __uint_as_float(u.y & 0xFFFF0000u);
    a4 += __uint_as_float(u.z << 16);
    a5 += __uint_as_float(u.z & 0xFFFF0000u);
    a6 += __uint_as_float(u.w << 16);
    a7 += __uint_as_float(u.w & 0xFFFF0000u);
  }
  a0 += __shfl_xor(a0, 16, 64); a0 += __shfl_xor(a0, 32, 64);
  a1 += __shfl_xor(a1, 16, 64); a1 += __shfl_xor(a1, 32, 64);
  a2 += __shfl_xor(a2, 16, 64); a2 += __shfl_xor(a2, 32, 64);
  a3 += __shfl_xor(a3, 16, 64); a3 += __shfl_xor(a3, 32, 64);
  a4 += __shfl_xor(a4, 16, 64); a4 += __shfl_xor(a4, 32, 64);
  a5 += __shfl_xor(a5, 16, 64); a5 += __shfl_xor(a5, 32, 64);
  a6 += __shfl_xor(a6, 16, 64); a6 += __shfl_xor(a6, 32, 64);
  a7 += __shfl_xor(a7, 16, 64); a7 += __shfl_xor(a7, 32, 64);
  if (qt == 0) {
    float inv = 1.0f / (float)(deg > 0 ? deg : 1);
    uint4 o;
    o.x = pack2(a0 * inv, a1 * inv);
    o.y = pack2(a2 * inv, a3 * inv);
    o.z = pack2(a4 * inv, a5 * inv);
    o.w = pack2(a6 * inv, a7 * inv);
    *reinterpret_cast<uint4*>(&outv[(size_t)node * (FF / 2) + li * 4]) = o;
  }
}

// ---------- tiled SGEMM (f32) — compress only (EPI 0, DUAL, fused score) ----------
template <int EPI, bool DUAL, bool ABF16>
__global__ __launch_bounds__(256) void k_gemm4(const void* __restrict__ Araw,
                                               const float* __restrict__ W,
                                               const float* __restrict__ A2,
                                               const float* __restrict__ W2,
                                               const float* __restrict__ bias,
                                               float* __restrict__ outv,
                                               const float* __restrict__ wsc,
                                               const float* __restrict__ bsc,
                                               float* __restrict__ score_out) {
  __shared__ float As[BK][BM + 4];
  __shared__ float Ws[BK][FF];
  const int tid = threadIdx.x;
  const int tx = tid & 15;
  const int ty = tid >> 4;
  const int m0 = blockIdx.x * BM;

  float acc[4][8];
#pragma unroll
  for (int r = 0; r < 4; ++r)
#pragma unroll
    for (int j = 0; j < 8; ++j) acc[r][j] = 0.f;

  const int NPASS = DUAL ? 2 : 1;
  for (int pass = 0; pass < NPASS; ++pass) {
    const float* Wp = (pass == 0) ? W : W2;
    for (int kt = 0; kt < FF; kt += BK) {
      __syncthreads();
      if (pass == 0 && ABF16) {
        const unsigned* Ab = (const unsigned*)Araw;
#pragma unroll
        for (int t = 0; t < 4; ++t) {
          int i = tid + t * 256;
          int row = i >> 4;
          int cu = i & 15;
          int gr = m0 + row;
          unsigned u = (gr < NN) ? Ab[(size_t)gr * (FF / 2) + (kt >> 1) + cu] : 0u;
          As[cu * 2 + 0][row] = __uint_as_float(u << 16);
          As[cu * 2 + 1][row] = __uint_as_float(u & 0xFFFF0000u);
        }
      } else {
        const float* Ag = (pass == 0) ? (const float*)Araw : A2;
#pragma unroll
        for (int t = 0; t < 2; ++t) {
          int i = tid + t * 256;
          int row = i >> 3;
          int c8 = i & 7;
          int gr = m0 + row;
          float4 v = make_float4(0.f, 0.f, 0.f, 0.f);
          if (gr < NN) v = *(const float4*)&Ag[(size_t)gr * FF + kt + c8 * 4];
          As[c8 * 4 + 0][row] = v.x;
          As[c8 * 4 + 1][row] = v.y;
          As[c8 * 4 + 2][row] = v.z;
          As[c8 * 4 + 3][row] = v.w;
        }
      }
#pragma unroll
      for (int t = 0; t < 4; ++t) {
        int i = tid + t * 256;
        int kr = i >> 5;
        int c4 = i & 31;
        *(float4*)&Ws[kr][c4 * 4] =
            *(const float4*)&Wp[(size_t)(kt + kr) * FF + c4 * 4];
      }
      __syncthreads();
#pragma unroll
      for (int k = 0; k < BK; ++k) {
        float4 a = *(const float4*)&As[k][ty * 4];
        float4 w0 = *(const float4*)&Ws[k][tx * 4];
        float4 w1 = *(const float4*)&Ws[k][tx * 4 + 64];
        float av[4] = {a.x, a.y, a.z, a.w};
        float wv[8] = {w0.x, w0.y, w0.z, w0.w, w1.x, w1.y, w1.z, w1.w};
#pragma unroll
        for (int r = 0; r < 4; ++r)
#pragma unroll
          for (int j = 0; j < 8; ++j) acc[r][j] = fmaf(av[r], wv[j], acc[r][j]);
      }
    }
  }

  float4 b0 = *(const float4*)&bias[tx * 4];
  float4 b1 = *(const float4*)&bias[tx * 4 + 64];
  float bs[8] = {b0.x, b0.y, b0.z, b0.w, b1.x, b1.y, b1.z, b1.w};

  if constexpr (EPI == 0) {
    __shared__ float sp[BM][17];
    float4 s0 = *(const float4*)&wsc[tx * 4];
    float4 s1 = *(const float4*)&wsc[tx * 4 + 64];
    float sv[8] = {s0.x, s0.y, s0.z, s0.w, s1.x, s1.y, s1.z, s1.w};
#pragma unroll
    for (int r = 0; r < 4; ++r) {
      int gi = m0 + ty * 4 + r;
      if (gi >= NN) continue;
      size_t base = (size_t)gi * FF;
      float v[8];
      float p = 0.f;
#pragma unroll
      for (int j = 0; j < 8; ++j) {
        v[j] = acc[r][j] + bs[j];
        p = fmaf(v[j], sv[j], p);
      }
      sp[ty * 4 + r][tx] = p;
      *(float4*)&outv[base + tx * 4] = make_float4(v[0], v[1], v[2], v[3]);
      *(float4*)&outv[base + tx * 4 + 64] = make_float4(v[4], v[5], v[6], v[7]);
    }
    __syncthreads();
    if (tid < BM) {
      int gi = m0 + tid;
      if (gi < NN) {
        float s = 0.f;
#pragma unroll
        for (int t = 0; t < 16; ++t) s += sp[tid][t];  // fixed order
        float z = s + bsc[0];
        score_out[gi] = 1.0f / (1.0f + expf(-z));
      }
    }
  }
}

// ---------- pack W (f32 [128][128]) into MFMA B-fragment bf16 layout ----------
__global__ __launch_bounds__(256) void k_packW(const float* __restrict__ W,
                                               unsigned* __restrict__ Wpk) {
  int i = blockIdx.x * 256 + threadIdx.x;  // 0..2047
  int kt = i >> 9;
  int rem = i & 511;
  int c = rem >> 2;
  int h = rem & 3;
  int kb = kt * 32 + h * 8;
  uint4 o;
  o.x = pack2(W[(kb + 0) * FF + c], W[(kb + 1) * FF + c]);
  o.y = pack2(W[(kb + 2) * FF + c], W[(kb + 3) * FF + c]);
  o.z = pack2(W[(kb + 4) * FF + c], W[(kb + 5) * FF + c]);
  o.w = pack2(W[(kb + 6) * FF + c], W[(kb + 7) * FF + c]);
  *reinterpret_cast<uint4*>(&Wpk[(size_t)i * 4]) = o;
}

// ---------- MFMA bf16 GEMM for decompress (round-13 verified) ----------
template <int EPI>
__global__ __launch_bounds__(256) void k_gemm_mfma(const unsigned* __restrict__ A,
                                                   const unsigned* __restrict__ Wpk,
                                                   const float* __restrict__ bias,
                                                   const float* __restrict__ aux,
                                                   const float* __restrict__ score,
                                                   const float* __restrict__ sel,
                                                   float* __restrict__ outv,
                                                   unsigned short* __restrict__ obf) {
  __shared__ unsigned As[64][68];
  const int tid = threadIdx.x;
  const int wv = tid >> 6;
  const int l = tid & 63;
  const int lg = l >> 4;
  const int lr = l & 15;
  const int m0 = blockIdx.x * 64;

#pragma unroll
  for (int p = 0; p < 4; ++p) {
    int i = tid + p * 256;
    int row = i >> 4, c4 = (i & 15) * 4;
    int gr = m0 + row;
    uint4 v = make_uint4(0u, 0u, 0u, 0u);
    if (gr < NN) v = *reinterpret_cast<const uint4*>(&A[(size_t)gr * 64 + c4]);
    *reinterpret_cast<uint4*>(&As[row][c4]) = v;
  }
  __syncthreads();

  int arow = wv * 16 + lr;
  short8v a[4];
#pragma unroll
  for (int kt = 0; kt < 4; ++kt)
    a[kt] = *reinterpret_cast<const short8v*>(&As[arow][kt * 16 + lg * 4]);

#pragma unroll
  for (int ct = 0; ct < 8; ++ct) {
    float4v acc = {0.f, 0.f, 0.f, 0.f};
    int col = ct * 16 + lr;
#pragma unroll
    for (int kt = 0; kt < 4; ++kt) {
      short8v b = *reinterpret_cast<const short8v*>(
          &Wpk[(size_t)((kt * 128 + col) * 4 + lg) * 4]);
      acc = __builtin_amdgcn_mfma_f32_16x16x32_bf16(a[kt], b, acc, 0, 0, 0);
    }
    float bcol = bias[col];
#pragma unroll
    for (int i = 0; i < 4; ++i) {
      int gi = m0 + wv * 16 + lg * 4 + i;
      if (gi >= NN) continue;
      float g = acc[i] + bcol;
      size_t oi = (size_t)gi * FF + col;
      if (EPI == 1) {
        float se = sel[gi];
        float v;
        if (se != 0.f) {
          v = fmaxf(aux[oi] * score[gi], 0.f);
          outv[oi] = v;
        } else {
          v = fmaxf(g, 0.f);
        }
        obf[(size_t)gi * FF + col] = f2b(v);
      } else {
        float se = sel[gi];
        outv[oi] = (se != 0.f) ? aux[oi] : g;
      }
    }
  }
}

// ===== top-K: 4x8-bit radix on score bits + analytic lowest-index tie-break =====
__global__ void k_init_state(unsigned* state) {
  state[0] = 0u;   // 32-bit score-bit prefix
  state[1] = KK;   // remaining rank
}

__global__ __launch_bounds__(256) void k_hist(const float* __restrict__ score,
                                              const unsigned* __restrict__ state,
                                              unsigned* __restrict__ hist,
                                              int bits_fixed) {
  __shared__ unsigned lh[256];
  lh[threadIdx.x] = 0;
  __syncthreads();
  unsigned prefix = state[0];
  int i = blockIdx.x * 256 + threadIdx.x;
  if (i < NN) {
    unsigned bits = __float_as_uint(score[i]);
    bool ok = (bits_fixed == 0) ? true
                                : (((bits ^ prefix) >> (32 - bits_fixed)) == 0u);
    if (ok) {
      unsigned b = (bits >> (24 - bits_fixed)) & 0xFFu;
      atomicAdd(&lh[b], 1u);
    }
  }
  __syncthreads();
  if (lh[threadIdx.x]) atomicAdd(&hist[threadIdx.x], lh[threadIdx.x]);
}

__global__ __launch_bounds__(256) void k_select_round(unsigned* __restrict__ state,
                                                      unsigned* __restrict__ hist,
                                                      int bits_fixed) {
  __shared__ unsigned h[256];
  int t = threadIdx.x;
  h[t] = hist[t];
  hist[t] = 0;  // ready for next round
  __syncthreads();
  if (t == 0) {
    unsigned rem = state[1];
    unsigned prefix = state[0];
    unsigned cum = 0;
    int bstar = 0;
    for (int b = 255; b >= 0; --b) {
      unsigned c = h[b];
      if (cum + c >= rem) { bstar = b; break; }
      cum += c;
    }
    rem -= cum;
    prefix |= ((unsigned)bstar) << (24 - bits_fixed);
    state[0] = prefix;
    state[1] = rem;
  }
}

__global__ __launch_bounds__(256) void k_eqcount(const float* __restrict__ score,
                                                 const unsigned* __restrict__ state,
                                                 int* __restrict__ eqc) {
  __shared__ int s[256];
  int i = blockIdx.x * 256 + threadIdx.x;
  unsigned T = state[0];
  int eq = (i < NN && __float_as_uint(score[i]) == T) ? 1 : 0;
  s[threadIdx.x] = eq;
  __syncthreads();
  for (int off = 128; off > 0; off >>= 1) {
    if (threadIdx.x < off) s[threadIdx.x] += s[threadIdx.x + off];
    __syncthreads();
  }
  if (threadIdx.x == 0) eqc[blockIdx.x] = s[0];
}

__global__ __launch_bounds__(512) void k_eqscan(const int* __restrict__ eqc,
                                                int* __restrict__ eqoff) {
  __shared__ int s[512];
  __shared__ int tmp[512];
  int t = threadIdx.x;
  int own = (t < NB) ? eqc[t] : 0;
  s[t] = own;
  __syncthreads();
  int* A = s;
  int* B = tmp;
  for (int off = 1; off < 512; off <<= 1) {
    int v = A[t] + (t >= off ? A[t - off] : 0);
    B[t] = v;
    __syncthreads();
    int* sw = A; A = B; B = sw;
  }
  if (t < NB) eqoff[t] = A[t] - own;  // exclusive
}

__global__ __launch_bounds__(256) void k_tb(const float* __restrict__ score,
                                            const unsigned* __restrict__ state,
                                            const int* __restrict__ eqoff,
                                            float* __restrict__ sel) {
  __shared__ int s[256];
  __shared__ int tmp[256];
  int blk = blockIdx.x;
  int i = blk * 256 + threadIdx.x;
  unsigned T = state[0];
  unsigned rem = state[1];
  unsigned bits = (i < NN) ? __float_as_uint(score[i]) : 0u;
  int eq = (i < NN && bits == T) ? 1 : 0;
  s[threadIdx.x] = eq;
  __syncthreads();
  int* A = s;
  int* B = tmp;
  for (int off = 1; off < 256; off <<= 1) {
    int v = A[threadIdx.x] + (threadIdx.x >= off ? A[threadIdx.x - off] : 0);
    B[threadIdx.x] = v;
    __syncthreads();
    int* sw = A; A = B; B = sw;
  }
  int excl = A[threadIdx.x] - eq;
  if (i < NN) {
    float sv = 0.f;
    if (bits > T) sv = 1.f;
    else if (eq && (unsigned)(eqoff[blk] + excl) < rem) sv = 1.f;
    sel[i] = sv;
  }
}

// ---------- gated z pack (reads sel; selected rows only) ----------
__global__ __launch_bounds__(256) void k_gate_zg(const float* __restrict__ h,
                                                 const float* __restrict__ score,
                                                 const float* __restrict__ sel,
                                                 unsigned* __restrict__ zg) {
  int w = threadIdx.x >> 6;
  int lane = threadIdx.x & 63;
  int node = blockIdx.x * 4 + w;
  if (node >= NN) return;
  if (sel[node] == 0.f) return;
  float s = score[node];
  float2 v = *reinterpret_cast<const float2*>(&h[(size_t)node * FF + lane * 2]);
  zg[(size_t)node * (FF / 2) + lane] = pack2(v.x * s, v.y * s);
}

// ---------- launch ----------
extern "C" void kernel_launch(void* const* d_in, const int* in_sizes, int n_in,
                              void* d_out, int out_size, void* d_ws, size_t ws_size,
                              hipStream_t stream) {
  const float* x = (const float*)d_in[0];
  const int* src = (const int*)d_in[1];
  const int* tgt = (const int*)d_in[2];
  const float* W_self = (const float*)d_in[3];
  const float* W_neigh = (const float*)d_in[4];
  const float* b_pack = (const float*)d_in[5];
  const float* w_score = (const float*)d_in[6];
  const float* b_score = (const float*)d_in[7];
  const float* W_u1 = (const float*)d_in[8];
  const float* b_u1 = (const float*)d_in[9];
  const float* W_u2 = (const float*)d_in[10];
  const float* b_u2 = (const float*)d_in[11];
  float* out = (float*)d_out;

  char* ws = (char*)d_ws;
  size_t off = 0;
  auto alloc = [&](size_t bytes) -> char* {
    char* p = ws + off;
    off += (bytes + 255) & ~(size_t)255;
    return p;
  };
  int* offsets = (int*)alloc((size_t)(NN + 1) * 4);
  int* csr = (int*)alloc((size_t)NE * 4);
  int* histg = (int*)alloc((size_t)NBKT2 * NBLKA * 4);
  int* bbase = (int*)alloc((size_t)(NBKT2 + 1) * 4);
  float* score = (float*)alloc((size_t)NN * 4);
  float* sel = (float*)alloc((size_t)NN * 4);
  unsigned* hist = (unsigned*)alloc(256 * 4);
  unsigned* state = (unsigned*)alloc(64);
  int* eqc = (int*)alloc((size_t)NB * 4);
  int* eqoff = (int*)alloc((size_t)NB * 4);
  unsigned* pkW1 = (unsigned*)alloc(2048 * 16);
  unsigned* pkW2 = (unsigned*)alloc(2048 * 16);
  float* aggF = (float*)alloc((size_t)NN * FF * 4);  // 51.2 MB, multi-use:
  int* pairs = (int*)aggF;                            //   CSR build scratch (6.4 MB)
  unsigned* zdbf = (unsigned*)aggF;                   //   then z-bf16 / d-bf16
  unsigned* aggBF = (unsigned*)(aggF + (size_t)NN * (FF / 2));  // bf16 agg out
  float* bufB = out;  // h, then d, live in d_out

  hipMemsetAsync(hist, 0, 256 * 4, stream);
  k_init_state<<<1, 1, 0, stream>>>(state);
  k_packW<<<8, 256, 0, stream>>>(W_u1, pkW1);
  k_packW<<<8, 256, 0, stream>>>(W_u2, pkW2);

  // radix CSR build: histogram -> scan -> scatter packed pairs -> per-bucket fill
  k_histA<<<NBLKA, 256, 0, stream>>>(tgt, histg);
  k_scanA<<<1, 1024, 0, stream>>>(histg, bbase);
  k_scatterA<<<NBLKA, 256, 0, stream>>>(src, tgt, histg, pairs);
  k_bucketB<<<NBKT2, 1024, 0, stream>>>(pairs, bbase, offsets, csr);

  // ---- compress (f32; score fused into gemm0 epilogue) ----
  k_agg<<<NN / 4, 256, 0, stream>>>(x, csr, offsets, aggF);
  k_gemm4<0, true, false><<<GEMM_GRID, 256, 0, stream>>>(
      aggF, W_neigh, x, W_self, b_pack, bufB, w_score, b_score, score);

  // ---- exact top-K: 4x8-bit radix (LDS-aggregated hist) + lowest-index tie-break
  for (int r = 0; r < 4; ++r) {
    k_hist<<<NB, 256, 0, stream>>>(score, state, hist, 8 * r);
    k_select_round<<<1, 256, 0, stream>>>(state, hist, 8 * r);
  }
  k_eqcount<<<NB, 256, 0, stream>>>(score, state, eqc);
  k_eqscan<<<1, 512, 0, stream>>>(eqc, eqoff);
  k_tb<<<NB, 256, 0, stream>>>(score, state, eqoff, sel);

  // ---- decompress (bf16 gathers + MFMA bf16 GEMMs; selected rows stay f32) ----
  k_gate_zg<<<NN / 4, 256, 0, stream>>>(bufB, score, sel, zdbf);
  k_agg_bf<true><<<NN / 4, 256, 0, stream>>>(zdbf, csr, offsets, sel, aggBF);
  k_gemm_mfma<1><<<GEMM_GRID, 256, 0, stream>>>(aggBF, pkW1, b_u1, bufB, score,
                                                sel, bufB,
                                                (unsigned short*)zdbf);
  k_agg_bf<false><<<NN / 4, 256, 0, stream>>>(zdbf, csr, offsets, nullptr, aggBF);
  k_gemm_mfma<2><<<GEMM_GRID, 256, 0, stream>>>(aggBF, pkW2, b_u2, bufB, nullptr,
                                                sel, out, nullptr);
}